// Round 1
// baseline (1281.059 us; speedup 1.0000x reference)
//
#include <hip/hip_runtime.h>
#include <hip/hip_bf16.h>
#include <cstddef>

#define IN_C 256
#define OUT_C 64
#define NEG_SLOPE 0.2f
#define TILE_NODES 32   // nodes per block in projection kernel (8 per wave x 4 waves)

// ---------------------------------------------------------------------------
// Kernel 1: h = x @ W^T, s_i = h@a_i, s_j = h@a_j, plus self-loop init of
// denom and out.  W^T staged in LDS (64 KB, conflict-free access), 8 nodes
// per wave register-blocked, x read as wave-uniform float4 (L1 broadcast).
// ---------------------------------------------------------------------------
__global__ __launch_bounds__(256) void fused_h_kernel(
    const float* __restrict__ x, const float* __restrict__ W,
    const float* __restrict__ a, float* __restrict__ h,
    float* __restrict__ s_i, float* __restrict__ s_j,
    float* __restrict__ denom, float* __restrict__ out, int n_nodes)
{
    __shared__ float Wt[IN_C * OUT_C];   // Wt[k*64 + c] = W[c][k]

    const int tid = threadIdx.x;
    // Stage W transposed: coalesced global read, scattered LDS write (one-time)
    for (int i = tid; i < OUT_C * IN_C; i += 256) {
        int c = i >> 8;          // row of W (output channel)
        int k = i & (IN_C - 1);  // col of W (input channel)
        Wt[k * OUT_C + c] = W[i];
    }
    __syncthreads();

    const int lane = tid & 63;
    const int wv   = tid >> 6;
    const float ai = a[lane];           // a[:64]
    const float aj = a[OUT_C + lane];   // a[64:]

    const int tiles = (n_nodes + TILE_NODES - 1) / TILE_NODES;
    for (int t = blockIdx.x; t < tiles; t += gridDim.x) {
        const int base = t * TILE_NODES + wv * 8;

        float acc[8];
        #pragma unroll
        for (int m = 0; m < 8; ++m) acc[m] = 0.f;

        // K loop, unrolled by 4; x loads are wave-uniform float4 broadcasts
        for (int k = 0; k < IN_C; k += 4) {
            const float w0 = Wt[(k + 0) * OUT_C + lane];
            const float w1 = Wt[(k + 1) * OUT_C + lane];
            const float w2 = Wt[(k + 2) * OUT_C + lane];
            const float w3 = Wt[(k + 3) * OUT_C + lane];
            #pragma unroll
            for (int m = 0; m < 8; ++m) {
                int node = base + m;
                if (node >= n_nodes) node = n_nodes - 1;  // clamp (safe read)
                const float4 xv = *(const float4*)(x + (size_t)node * IN_C + k);
                acc[m] += xv.x * w0 + xv.y * w1 + xv.z * w2 + xv.w * w3;
            }
        }

        // Epilogue: per-node s_i/s_j wave reductions + self-loop init
        #pragma unroll
        for (int m = 0; m < 8; ++m) {
            const int node = base + m;
            const bool valid = (node < n_nodes);
            const float hv = acc[m];
            float pi = hv * ai;
            float pj = hv * aj;
            #pragma unroll
            for (int off = 32; off > 0; off >>= 1) {
                pi += __shfl_xor(pi, off, 64);
                pj += __shfl_xor(pj, off, 64);
            }
            // self-loop: row = col = node -> e = lrelu(s_i[node] + s_j[node])
            const float es = pi + pj;
            const float e  = (es >= 0.f) ? es : NEG_SLOPE * es;
            const float ex = __expf(e);
            if (valid) {
                h[(size_t)node * OUT_C + lane]   = hv;
                out[(size_t)node * OUT_C + lane] = ex * hv;  // init accumulator
                if (lane == 0) {
                    s_i[node]   = pi;
                    s_j[node]   = pj;
                    denom[node] = ex;   // init with self-loop weight
                }
            }
        }
    }
}

// ---------------------------------------------------------------------------
// Kernel 2: one wave per edge.  ex = exp(lrelu(s_i[col]+s_j[row]));
// out[col][:] += ex * h[row][:]  (per-lane atomics, coalesced 256B groups);
// denom[col] += ex (lane 0).
// ---------------------------------------------------------------------------
__global__ __launch_bounds__(256) void edge_kernel(
    const int* __restrict__ ei, const float* __restrict__ h,
    const float* __restrict__ s_i, const float* __restrict__ s_j,
    float* __restrict__ out, float* __restrict__ denom, int n_edges)
{
    const int wid  = (int)((blockIdx.x * (unsigned)blockDim.x + threadIdx.x) >> 6);
    const int lane = threadIdx.x & 63;
    if (wid >= n_edges) return;

    const int r = ei[wid];             // edge_index[0][e] -> row (source)
    const int c = ei[n_edges + wid];   // edge_index[1][e] -> col (dest)

    const float es = s_i[c] + s_j[r];
    const float e  = (es >= 0.f) ? es : NEG_SLOPE * es;
    const float ex = __expf(e);

    const float hv = h[(size_t)r * OUT_C + lane];
    atomicAdd(out + (size_t)c * OUT_C + lane, ex * hv);
    if (lane == 0) atomicAdd(denom + c, ex);
}

// ---------------------------------------------------------------------------
// Kernel 3: out[i][c] /= denom[i]
// ---------------------------------------------------------------------------
__global__ __launch_bounds__(256) void norm_kernel(
    float* __restrict__ out, const float* __restrict__ denom, int n_total)
{
    const int i = blockIdx.x * 256 + threadIdx.x;
    if (i < n_total) {
        out[i] = out[i] / denom[i >> 6];
    }
}

extern "C" void kernel_launch(void* const* d_in, const int* in_sizes, int n_in,
                              void* d_out, int out_size, void* d_ws, size_t ws_size,
                              hipStream_t stream)
{
    const float* x  = (const float*)d_in[0];
    const int*   ei = (const int*)d_in[1];
    const float* W  = (const float*)d_in[2];
    const float* a  = (const float*)d_in[3];
    // d_in[4] = num_nodes (device scalar) — shape known from in_sizes instead.

    const int N = in_sizes[0] / IN_C;   // 100000
    const int E = in_sizes[1] / 2;      // 3200000

    float* out   = (float*)d_out;
    float* h     = (float*)d_ws;                       // N*64 floats (25.6 MB)
    float* s_i   = h + (size_t)N * OUT_C;              // N floats
    float* s_j   = s_i + N;                            // N floats
    float* denom = s_j + N;                            // N floats

    // 1. projection + scores + self-loop init (fully writes out, denom, h, s_*)
    const int tiles = (N + TILE_NODES - 1) / TILE_NODES;
    hipLaunchKernelGGL(fused_h_kernel, dim3(tiles), dim3(256), 0, stream,
                       x, W, a, h, s_i, s_j, denom, out, N);

    // 2. edge scatter-aggregate (one wave per edge)
    const int eblocks = (E + 3) / 4;   // 4 waves per 256-thread block
    hipLaunchKernelGGL(edge_kernel, dim3(eblocks), dim3(256), 0, stream,
                       ei, h, s_i, s_j, out, denom, E);

    // 3. normalize
    const int n_total = N * OUT_C;
    hipLaunchKernelGGL(norm_kernel, dim3((n_total + 255) / 256), dim3(256), 0, stream,
                       out, denom, n_total);
}

// Round 2
// 819.541 us; speedup vs baseline: 1.5631x; 1.5631x over previous
//
#include <hip/hip_runtime.h>
#include <hip/hip_bf16.h>
#include <cstddef>

#define IN_C 256
#define OUT_C 64
#define NEG_SLOPE 0.2f
#define TILE 16          // nodes per block-tile in projection kernel

// ---------------------------------------------------------------------------
// Kernel 1: h = x @ W^T, s_i = h@a_i, s_j = h@a_j.
// W^T (64 KB) + x tile (16 KB) in LDS = 80 KB -> 2 blocks/CU.
// x staged with coalesced float4 loads; inner loop reads x as LDS broadcast.
// ---------------------------------------------------------------------------
__global__ __launch_bounds__(256) void fused_h_kernel(
    const float* __restrict__ x, const float* __restrict__ W,
    const float* __restrict__ a, float* __restrict__ h,
    float* __restrict__ s_i, float* __restrict__ s_j, int n_nodes)
{
    __shared__ float Wt[IN_C * OUT_C];   // Wt[k*64 + c] = W[c][k]  (64 KB)
    __shared__ float xs[TILE * IN_C];    // 16 KB

    const int tid = threadIdx.x;
    for (int i = tid; i < OUT_C * IN_C; i += 256) {
        int c = i >> 8;          // row of W (output channel)
        int k = i & (IN_C - 1);  // col of W (input channel)
        Wt[k * OUT_C + c] = W[i];
    }
    // Wt-use is protected by the __syncthreads() after xs staging below.

    const int lane = tid & 63;
    const int wv   = tid >> 6;
    const float ai = a[lane];
    const float aj = a[OUT_C + lane];

    const int tiles = (n_nodes + TILE - 1) / TILE;
    for (int t = blockIdx.x; t < tiles; t += gridDim.x) {
        const int base = t * TILE;
        __syncthreads();   // protect xs from previous iteration's readers
        // stage x tile: 16 rows x 64 float4; 1024 float4 total, 4 per thread
        for (int i = tid; i < TILE * (IN_C / 4); i += 256) {
            const int node = base + (i >> 6);
            const int k4   = i & 63;
            float4 v = make_float4(0.f, 0.f, 0.f, 0.f);
            if (node < n_nodes)
                v = ((const float4*)x)[(size_t)node * (IN_C / 4) + k4];
            ((float4*)xs)[i] = v;
        }
        __syncthreads();

        float acc[4] = {0.f, 0.f, 0.f, 0.f};
        for (int k = 0; k < IN_C; k += 4) {
            const float w0 = Wt[(k + 0) * OUT_C + lane];
            const float w1 = Wt[(k + 1) * OUT_C + lane];
            const float w2 = Wt[(k + 2) * OUT_C + lane];
            const float w3 = Wt[(k + 3) * OUT_C + lane];
            #pragma unroll
            for (int m = 0; m < 4; ++m) {
                const float4 xv = ((const float4*)xs)[(wv * 4 + m) * (IN_C / 4) + (k >> 2)];
                acc[m] += xv.x * w0 + xv.y * w1 + xv.z * w2 + xv.w * w3;
            }
        }

        #pragma unroll
        for (int m = 0; m < 4; ++m) {
            const int node = base + wv * 4 + m;
            const float hv = acc[m];
            float pi = hv * ai;
            float pj = hv * aj;
            #pragma unroll
            for (int off = 32; off > 0; off >>= 1) {
                pi += __shfl_xor(pi, off, 64);
                pj += __shfl_xor(pj, off, 64);
            }
            if (node < n_nodes) {
                h[(size_t)node * OUT_C + lane] = hv;
                if (lane == 0) { s_i[node] = pi; s_j[node] = pj; }
            }
        }
    }
}

// ---------------------------------------------------------------------------
// CSR build: zero, histogram of col, hierarchical exclusive scan, scatter.
// ---------------------------------------------------------------------------
__global__ __launch_bounds__(256) void zero_kernel(int* __restrict__ p, int n)
{
    const int i = blockIdx.x * 256 + threadIdx.x;
    if (i < n) p[i] = 0;
}

__global__ __launch_bounds__(256) void hist_kernel(
    const int* __restrict__ ei, int* __restrict__ counts, int n_edges)
{
    const int e = blockIdx.x * 256 + threadIdx.x;
    if (e < n_edges) atomicAdd(&counts[ei[n_edges + e]], 1);
}

// 1024 elements per block: per-thread 4, Hillis-Steele over 256 thread sums.
__global__ __launch_bounds__(256) void scan1_kernel(
    const int* __restrict__ counts, int* __restrict__ offsets,
    int* __restrict__ bsum, int n)
{
    __shared__ int sd[256];
    const int tid  = threadIdx.x;
    const int base = blockIdx.x * 1024 + tid * 4;
    int v[4]; int ts = 0;
    #pragma unroll
    for (int j = 0; j < 4; ++j) {
        const int i = base + j;
        v[j] = (i < n) ? counts[i] : 0;
        ts += v[j];
    }
    sd[tid] = ts;
    __syncthreads();
    for (int off = 1; off < 256; off <<= 1) {
        const int mine  = sd[tid];
        const int other = (tid >= off) ? sd[tid - off] : 0;
        __syncthreads();
        sd[tid] = mine + other;
        __syncthreads();
    }
    int run = sd[tid] - ts;  // exclusive prefix of this thread's chunk
    #pragma unroll
    for (int j = 0; j < 4; ++j) {
        const int i = base + j;
        if (i < n) offsets[i] = run;
        run += v[j];
    }
    if (tid == 255) bsum[blockIdx.x] = sd[255];
}

__global__ void scan2_kernel(int* __restrict__ bsum, int nblk)
{
    if (threadIdx.x == 0 && blockIdx.x == 0) {
        int running = 0;
        for (int b = 0; b < nblk; ++b) {
            const int t = bsum[b];
            bsum[b] = running;
            running += t;
        }
    }
}

__global__ __launch_bounds__(256) void scan3_kernel(
    int* __restrict__ offsets, int* __restrict__ cursor,
    const int* __restrict__ bsum, int n)
{
    const int i = blockIdx.x * 256 + threadIdx.x;
    if (i < n) {
        const int val = offsets[i] + bsum[i >> 10];
        offsets[i] = val;
        cursor[i]  = val;
    }
}

__global__ __launch_bounds__(256) void scatter_kernel(
    const int* __restrict__ ei, int* __restrict__ cursor,
    int* __restrict__ erow, int n_edges)
{
    const int e = blockIdx.x * 256 + threadIdx.x;
    if (e < n_edges) {
        const int r = ei[e];
        const int c = ei[n_edges + e];
        const int pos = atomicAdd(&cursor[c], 1);
        erow[pos] = r;
    }
}

// ---------------------------------------------------------------------------
// Gather-aggregate: one wave per destination node; no atomics.
// acc[lane] = sum_e exp(lrelu(s_i[col]+s_j[row])) * h[row][lane]  (+ self loop)
// out = acc / dsum.  Scalar loads for row indices / s_j, one coalesced 256 B
// vector gather of h per edge, unroll-4 for memory-level parallelism.
// ---------------------------------------------------------------------------
__device__ __forceinline__ float lrelu_exp(float t)
{
    t = (t >= 0.f) ? t : NEG_SLOPE * t;
    return __expf(t);
}

__global__ __launch_bounds__(256) void gather_kernel(
    const int* __restrict__ erow, const float* __restrict__ h,
    const float* __restrict__ s_i, const float* __restrict__ s_j,
    const int* __restrict__ offsets, const int* __restrict__ counts,
    float* __restrict__ out, int n_nodes)
{
    int wid = (int)((blockIdx.x * (unsigned)blockDim.x + threadIdx.x) >> 6);
    wid = __builtin_amdgcn_readfirstlane(wid);
    if (wid >= n_nodes) return;
    const int lane = threadIdx.x & 63;

    const float sic = s_i[wid];
    // self loop: row = col = node
    const float ex0 = lrelu_exp(sic + s_j[wid]);
    float acc  = ex0 * h[(size_t)wid * OUT_C + lane];
    float dsum = ex0;

    const int start = offsets[wid];
    const int cnt   = counts[wid];

    int e = 0;
    for (; e + 4 <= cnt; e += 4) {
        const int r0 = erow[start + e + 0];
        const int r1 = erow[start + e + 1];
        const int r2 = erow[start + e + 2];
        const int r3 = erow[start + e + 3];
        const float sj0 = s_j[r0], sj1 = s_j[r1], sj2 = s_j[r2], sj3 = s_j[r3];
        const float h0 = h[(size_t)r0 * OUT_C + lane];
        const float h1 = h[(size_t)r1 * OUT_C + lane];
        const float h2 = h[(size_t)r2 * OUT_C + lane];
        const float h3 = h[(size_t)r3 * OUT_C + lane];
        const float e0 = lrelu_exp(sic + sj0);
        const float e1 = lrelu_exp(sic + sj1);
        const float e2 = lrelu_exp(sic + sj2);
        const float e3 = lrelu_exp(sic + sj3);
        acc  += e0 * h0 + e1 * h1 + e2 * h2 + e3 * h3;
        dsum += e0 + e1 + e2 + e3;
    }
    for (; e < cnt; ++e) {
        const int r = erow[start + e];
        const float ex = lrelu_exp(sic + s_j[r]);
        acc  += ex * h[(size_t)r * OUT_C + lane];
        dsum += ex;
    }

    out[(size_t)wid * OUT_C + lane] = acc / dsum;
}

extern "C" void kernel_launch(void* const* d_in, const int* in_sizes, int n_in,
                              void* d_out, int out_size, void* d_ws, size_t ws_size,
                              hipStream_t stream)
{
    const float* x  = (const float*)d_in[0];
    const int*   ei = (const int*)d_in[1];
    const float* W  = (const float*)d_in[2];
    const float* a  = (const float*)d_in[3];

    const int N = in_sizes[0] / IN_C;   // 100000
    const int E = in_sizes[1] / 2;      // 3200000

    float* out = (float*)d_out;

    // workspace carve-up (floats/ints are both 4 B)
    float* h       = (float*)d_ws;                     // N*64
    float* s_i     = h + (size_t)N * OUT_C;            // N
    float* s_j     = s_i + N;                          // N
    int*   counts  = (int*)(s_j + N);                  // N
    int*   offsets = counts + N;                       // N
    int*   cursor  = offsets + N;                      // N
    int*   bsum    = cursor + N;                       // nblk (<=1024)
    int*   erow    = bsum + 1024;                      // E

    // 1. projection + attention scores (persistent grid, 2 blocks/CU)
    hipLaunchKernelGGL(fused_h_kernel, dim3(512), dim3(256), 0, stream,
                       x, W, a, h, s_i, s_j, N);

    // 2. CSR build
    hipLaunchKernelGGL(zero_kernel, dim3((N + 255) / 256), dim3(256), 0, stream,
                       counts, N);
    hipLaunchKernelGGL(hist_kernel, dim3((E + 255) / 256), dim3(256), 0, stream,
                       ei, counts, E);
    const int nblk = (N + 1023) / 1024;
    hipLaunchKernelGGL(scan1_kernel, dim3(nblk), dim3(256), 0, stream,
                       counts, offsets, bsum, N);
    hipLaunchKernelGGL(scan2_kernel, dim3(1), dim3(64), 0, stream, bsum, nblk);
    hipLaunchKernelGGL(scan3_kernel, dim3((N + 255) / 256), dim3(256), 0, stream,
                       offsets, cursor, bsum, N);
    hipLaunchKernelGGL(scatter_kernel, dim3((E + 255) / 256), dim3(256), 0, stream,
                       ei, cursor, erow, E);

    // 3. gather-aggregate (one wave per node, atomic-free)
    hipLaunchKernelGGL(gather_kernel, dim3((N + 3) / 4), dim3(256), 0, stream,
                       erow, h, s_i, s_j, offsets, counts, out, N);
}